// Round 3
// baseline (574.000 us; speedup 1.0000x reference)
//
#include <hip/hip_runtime.h>

// ESN forward (collapsed): out[row, r] = (1 - lr) * tanh(dot(x[row, 0:8], w_in[r, 0:8]))
// row = b*T + t, rows = 256*4096 = 1048576, R = 128, I = 8.
// d (input 2) is dead: reference multiplies it by a zero state.
//
// Memory-bound: 512 MiB out + 32 MiB in -> ~90 us floor at 6.3 TB/s.

constexpr int kI    = 8;
constexpr int kR    = 128;
constexpr int kRows = 256 * 4096; // 1048576

// Native clang vector: __builtin_nontemporal_store requires a real vector
// type, not HIP_vector_type<float,4>.
typedef float v4f __attribute__((ext_vector_type(4)));

__global__ __launch_bounds__(256) void esn_kernel(
    const float* __restrict__ x,     // [kRows, 8]
    const float* __restrict__ w_in,  // [128, 8]
    const float* __restrict__ lr,    // [1]
    float* __restrict__ out)         // [kRows, 128]
{
    const float scale = 1.0f - lr[0];

    const int lane     = threadIdx.x & 31;  // 32 threads per row; lane covers r = lane*4 .. lane*4+3
    const int rowInBlk = threadIdx.x >> 5;  // 8 rows per block iteration

    // Load this lane's 4 w_in rows (32 consecutive floats) into registers once.
    float w[4][8];
    {
        const v4f* wp = (const v4f*)(w_in) + lane * 8; // lane*32 floats
#pragma unroll
        for (int j = 0; j < 4; ++j) {
            v4f a = wp[2 * j];
            v4f b = wp[2 * j + 1];
            w[j][0] = a.x; w[j][1] = a.y; w[j][2] = a.z; w[j][3] = a.w;
            w[j][4] = b.x; w[j][5] = b.y; w[j][6] = b.z; w[j][7] = b.w;
        }
    }

    // 32-bit indexing: max byte offset = 1048576*128*4 = 2^29 < 2^31.
    const int rowStride = (int)gridDim.x * 8;
    for (int row = (int)blockIdx.x * 8 + rowInBlk; row < kRows; row += rowStride) {
        const v4f* xp = (const v4f*)(x + row * kI);
        v4f x0 = xp[0];
        v4f x1 = xp[1];

        v4f o;
#pragma unroll
        for (int j = 0; j < 4; ++j) {
            float acc = x0.x * w[j][0];
            acc = fmaf(x0.y, w[j][1], acc);
            acc = fmaf(x0.z, w[j][2], acc);
            acc = fmaf(x0.w, w[j][3], acc);
            acc = fmaf(x1.x, w[j][4], acc);
            acc = fmaf(x1.y, w[j][5], acc);
            acc = fmaf(x1.z, w[j][6], acc);
            acc = fmaf(x1.w, w[j][7], acc);
            // tanh(a) = 1 - 2/(exp(2a)+1); exp(2a)->inf gives rcp->0 -> 1 (no NaN).
            float e  = __expf(2.0f * acc);
            float th = 1.0f - 2.0f * __builtin_amdgcn_rcpf(e + 1.0f);
            o[j] = scale * th;
        }

        // Streaming store: output is never re-read; skip L2 write-allocate.
        __builtin_nontemporal_store(o, (v4f*)(out + row * kR) + lane);
    }
}

extern "C" void kernel_launch(void* const* d_in, const int* in_sizes, int n_in,
                              void* d_out, int out_size, void* d_ws, size_t ws_size,
                              hipStream_t stream) {
    const float* x    = (const float*)d_in[0];
    const float* w_in = (const float*)d_in[1];
    // d_in[2] = d  -- unused (reference multiplies it by a zero state)
    const float* lr   = (const float*)d_in[3];
    float* out        = (float*)d_out;

    // 2048 blocks x 256 threads: 8 rows per block-iter, 64 grid-stride iters;
    // w_in register load amortized; ~8 blocks/CU residency on 256 CUs.
    esn_kernel<<<dim3(2048), dim3(256), 0, stream>>>(x, w_in, lr, out);
}